// Round 6
// baseline (167.336 us; speedup 1.0000x reference)
//
#include <hip/hip_runtime.h>
#include <math.h>

#define STRD  256
#define NFFT  1024
#define TIME_ 262144
#define NWIN  1021   // (262144 - 1024)/256 + 1
#define NPAIR 511    // pair p covers windows 2p, 2p+1
#define BATCH 32
#define TW_FLOAT2 1008   // 16*15 (stage-2) + 256*3 (stage-3) twiddles

// XOR swizzle for a float2 (b64) LDS array: bank-pair = idx mod 16.
// Hand-checked: all 6 access patterns in this kernel are <=2-way (free).
#define SW(i) ((i) ^ (((i) >> 4) & 15))

__device__ __forceinline__ float2 cmul(float2 a, float2 b) {
    return make_float2(a.x * b.x - a.y * b.y, a.x * b.y + a.y * b.x);
}
// z * (sqrt2/2)(1 - i)   == W16^2
__device__ __forceinline__ float2 mul_w2(float2 z) {
    const float c = 0.70710678118654752440f;
    return make_float2(c * (z.x + z.y), c * (z.y - z.x));
}
// z * (sqrt2/2)(-1 - i)  == W16^6
__device__ __forceinline__ float2 mul_w6(float2 z) {
    const float c = 0.70710678118654752440f;
    return make_float2(c * (z.y - z.x), -c * (z.x + z.y));
}
// z * (-i)               == W16^4
__device__ __forceinline__ float2 mul_mi(float2 z) { return make_float2(z.y, -z.x); }

// Forward 4-point DFT, natural order (verified in rounds 3-5).
__device__ __forceinline__ void dft4(float2 v[4]) {
    float2 a = make_float2(v[0].x + v[2].x, v[0].y + v[2].y);
    float2 b = make_float2(v[0].x - v[2].x, v[0].y - v[2].y);
    float2 c = make_float2(v[1].x + v[3].x, v[1].y + v[3].y);
    float2 d = make_float2(v[1].x - v[3].x, v[1].y - v[3].y);
    v[0] = make_float2(a.x + c.x, a.y + c.y);
    v[2] = make_float2(a.x - c.x, a.y - c.y);
    v[1] = make_float2(b.x + d.y, b.y - d.x);   // b - i*d
    v[3] = make_float2(b.x - d.y, b.y + d.x);   // b + i*d
}

// Forward 16-point DFT in registers: two radix-4 layers (Stockham N=16),
// internal twiddles are compile-time constants.
__device__ __forceinline__ void dft16(float2 v[16]) {
    float2 u[16];
#pragma unroll
    for (int t = 0; t < 4; ++t) {
        float2 q[4] = { v[t], v[t + 4], v[t + 8], v[t + 12] };
        dft4(q);
        u[4 * t + 0] = q[0]; u[4 * t + 1] = q[1];
        u[4 * t + 2] = q[2]; u[4 * t + 3] = q[3];
    }
    const float2 W1 = make_float2( 0.9238795325112867f, -0.3826834323650898f);
    const float2 W3 = make_float2( 0.3826834323650898f, -0.9238795325112867f);
    const float2 W9 = make_float2(-0.9238795325112867f,  0.3826834323650898f);
    {   // t=0: no twiddle
        float2 q[4] = { u[0], u[4], u[8], u[12] };
        dft4(q); v[0] = q[0]; v[4] = q[1]; v[8] = q[2]; v[12] = q[3];
    }
    {   // t=1: W16^{1,2,3}
        float2 q[4] = { u[1], cmul(u[5], W1), mul_w2(u[9]), cmul(u[13], W3) };
        dft4(q); v[1] = q[0]; v[5] = q[1]; v[9] = q[2]; v[13] = q[3];
    }
    {   // t=2: W16^{2,4,6}
        float2 q[4] = { u[2], mul_w2(u[6]), mul_mi(u[10]), mul_w6(u[14]) };
        dft4(q); v[2] = q[0]; v[6] = q[1]; v[10] = q[2]; v[14] = q[3];
    }
    {   // t=3: W16^{3,6,9}
        float2 q[4] = { u[3], cmul(u[7], W3), mul_w6(u[11]), cmul(u[15], W9) };
        dft4(q); v[3] = q[0]; v[7] = q[1]; v[11] = q[2]; v[15] = q[3];
    }
}

// Twiddle tables in d_ws:
//  [0, 240):    tw2[m*15 + (r-1)] = exp(-2pi i m r / 256),  m in [0,16), r in [1,16)
//  [240, 1008): tw3[m*3  + (r-1)] = exp(-2pi i m r / 1024), m in [0,256), r in [1,4)
__global__ __launch_bounds__(256) void fill_tw_kernel(float2* __restrict__ tw) {
    int i = threadIdx.x + blockIdx.x * 256;
    if (i >= TW_FLOAT2) return;
    float ang;
    if (i < 240) {
        int m = i / 15, r = i % 15 + 1;
        ang = -6.283185307179586f * (float)(m * r) / 256.0f;
    } else {
        int t = i - 240;
        int m = t / 3, r = t % 3 + 1;
        ang = -6.283185307179586f * (float)(m * r) / 1024.0f;
    }
    float s, c;
    sincosf(ang, &s, &c);
    tw[i] = make_float2(c, s);
}

// 1024-pt FFT, radix 16*16*4, one wave (64 threads) per window pair.
// Two-for-one real trick: s[n] = a[n] + i*b[n] (windows 2p, 2p+1);
// Re A[k] = (S[k].x + S[-k].x)/2, Re B[k] = (S[k].y + S[-k].y)/2.
template <int USE_TW>
__global__ __launch_bounds__(64) void StridedFourier_kernel(
    const float* __restrict__ x, float* __restrict__ out,
    const float2* __restrict__ tw)
{
    __shared__ float2 X[NFFT];   // single in-place buffer, 8 KB

    const int j = threadIdx.x;   // 0..63
    const int p = blockIdx.x;    // window pair
    const int b = blockIdx.y;    // batch
    const int wa = 2 * p;
    const bool wbv = (wa + 1) < NWIN;   // last pair is a singleton

    const float* src = x + (size_t)b * TIME_ + (size_t)wa * STRD;

    // Load 1280 samples (two overlapping windows) coalesced.
    float L[20];
#pragma unroll
    for (int r = 0; r < 16; ++r) L[r] = src[j + 64 * r];
#pragma unroll
    for (int r = 16; r < 20; ++r) L[r] = wbv ? src[j + 64 * r] : 0.0f;

    float2 v[16];
#pragma unroll
    for (int r = 0; r < 16; ++r) v[r] = make_float2(L[r], L[r + 4]);

    // ---- stage 1: radix-16, Ns=1 (no twiddle) ----
    dft16(v);
#pragma unroll
    for (int r = 0; r < 16; ++r) X[SW(16 * j + r)] = v[r];
    __syncthreads();

    // ---- stage 2: radix-16, Ns=16, twiddle W256^{m r} ----
    const int m2 = j & 15;
    const int q2 = j >> 4;
    float2 t2[15];
    if (USE_TW) {
#pragma unroll
        for (int r = 0; r < 15; ++r) t2[r] = tw[m2 * 15 + r];
    } else {
        float s, c;
        __sincosf(-6.283185307179586f * (float)m2 / 256.0f, &s, &c);
        t2[0] = make_float2(c, s);
#pragma unroll
        for (int r = 1; r < 15; ++r) t2[r] = cmul(t2[r - 1], t2[0]);
    }
#pragma unroll
    for (int r = 0; r < 16; ++r) v[r] = X[SW(j + 64 * r)];
    __syncthreads();                         // all reads done before overwrite
#pragma unroll
    for (int r = 1; r < 16; ++r) v[r] = cmul(v[r], t2[r - 1]);
    dft16(v);
#pragma unroll
    for (int r = 0; r < 16; ++r) X[SW(q2 * 256 + m2 + 16 * r)] = v[r];
    __syncthreads();

    // ---- stage 3: radix-4, Ns=256, 4 butterflies/thread (m = j + 64*bb) ----
    float2 q3[4][4];
    float2 w3v[4][3];
#pragma unroll
    for (int bb = 0; bb < 4; ++bb)
#pragma unroll
        for (int r = 0; r < 4; ++r) q3[bb][r] = X[SW(j + 64 * bb + 256 * r)];
    __syncthreads();                         // reads done before untangle writes
#pragma unroll
    for (int bb = 0; bb < 4; ++bb) {
        const int m = j + 64 * bb;
        if (USE_TW) {
#pragma unroll
            for (int r = 0; r < 3; ++r) w3v[bb][r] = tw[240 + m * 3 + r];
        } else {
            float s, c;
            __sincosf(-6.283185307179586f * (float)m / 1024.0f, &s, &c);
            w3v[bb][0] = make_float2(c, s);
            w3v[bb][1] = cmul(w3v[bb][0], w3v[bb][0]);
            w3v[bb][2] = cmul(w3v[bb][1], w3v[bb][0]);
        }
    }
#pragma unroll
    for (int bb = 0; bb < 4; ++bb) {
        q3[bb][1] = cmul(q3[bb][1], w3v[bb][0]);
        q3[bb][2] = cmul(q3[bb][2], w3v[bb][1]);
        q3[bb][3] = cmul(q3[bb][3], w3v[bb][2]);
        dft4(q3[bb]);                        // q3[bb][r] = S[j + 64bb + 256r]
    }

    // ---- untangle via LDS mirror ----
#pragma unroll
    for (int bb = 0; bb < 4; ++bb)
#pragma unroll
        for (int r = 0; r < 4; ++r) X[SW(j + 64 * bb + 256 * r)] = q3[bb][r];
    __syncthreads();

    const long long cbase = ((long long)b * NWIN + wa) * NFFT;
#pragma unroll
    for (int bb = 0; bb < 4; ++bb)
#pragma unroll
        for (int r = 0; r < 4; ++r) {
            int k = j + 64 * bb + 256 * r;
            int km = (NFFT - k) & (NFFT - 1);
            float2 M = X[SW(km)];
            out[cbase + k] = 0.5f * (q3[bb][r].x + M.x);
            if (wbv) out[cbase + NFFT + k] = 0.5f * (q3[bb][r].y + M.y);
        }
}

extern "C" void kernel_launch(void* const* d_in, const int* in_sizes, int n_in,
                              void* d_out, int out_size, void* d_ws, size_t ws_size,
                              hipStream_t stream) {
    const float* x = (const float*)d_in[0];
    float* out = (float*)d_out;
    float2* tw = (float2*)d_ws;
    dim3 grid(NPAIR, BATCH);
    if (ws_size >= TW_FLOAT2 * sizeof(float2)) {
        fill_tw_kernel<<<4, 256, 0, stream>>>(tw);
        StridedFourier_kernel<1><<<grid, 64, 0, stream>>>(x, out, tw);
    } else {
        StridedFourier_kernel<0><<<grid, 64, 0, stream>>>(x, out, tw);
    }
}